// Round 3
// baseline (137.983 us; speedup 1.0000x reference)
//
#include <hip/hip_runtime.h>

// RuleGraphConvLayer: LDS-staged bf16 A-tile + MFMA GEMM.
// out[i] = alive ? ([self_f | comb] @ [w_s; w_n[:81]]) : 0
//   sel  = idx1 ? idx1 : (idx0 ? idx0 : dead)
//   comb = [nei[0:3], self[3:81]+nei[3:81]] * (d2>0 ? 1/d2 : 1e4)
constexpr int kNodes = 262144;
constexpr int NC  = 103;   // feature columns
constexpr int F   = 81;    // used features
constexpr int OC  = 128;   // output channels
constexpr int NKS = 6;     // K steps: 6*32 = 192 >= 162
constexpr int KP  = 192;   // padded K
constexpr int LDK = 200;   // LDS row stride in bf16 (400 B: 16B-aligned rows, 2-way banks)
constexpr int NPB = 64;    // nodes per block
constexpr int THREADS = 256;

typedef __attribute__((ext_vector_type(8))) short bf16x8;
typedef __attribute__((ext_vector_type(4))) float f32x4;

__device__ inline ushort f2bf(float f) {
  uint u = __float_as_uint(f);
  return (ushort)((u + 0x7fffu + ((u >> 16) & 1u)) >> 16);  // RNE
}

// Weight table in B-fragment order: wf[ks][ct][lane] = 8 bf16 (16B/lane, coalesced).
// B[k][c]: k = ks*32 + (lane>>4)*8 + i, c = ct*16 + (lane&15).
__global__ __launch_bounds__(256)
void prep_w(const float* __restrict__ w_s, const float* __restrict__ w_n,
            ushort* __restrict__ wf) {
  int t = blockIdx.x * 256 + threadIdx.x;
  if (t >= NKS * 8 * 64) return;
  int l  = t & 63;
  int ct = (t >> 6) & 7;
  int ks = t >> 9;
  int c  = ct * 16 + (l & 15);
  int kb = ks * 32 + ((l >> 4) << 3);
  union { ushort u[8]; int4 v; } o;
  #pragma unroll
  for (int i = 0; i < 8; ++i) {
    int k = kb + i;
    float f = 0.f;
    if (k < F)          f = w_s[k * OC + c];
    else if (k < 2 * F) f = w_n[(k - F) * OC + c];
    o.u[i] = f2bf(f);
  }
  ((int4*)wf)[t] = o.v;
}

__global__ __launch_bounds__(THREADS)
void rgc_fused(const float* __restrict__ feat, const ushort* __restrict__ wf,
               float* __restrict__ out) {
  __shared__ ushort a_bf[NPB * LDK];   // 25600 B
  __shared__ float  s_cs[NPB];
  __shared__ float  s_alive[NPB];
  __shared__ int    s_sel[NPB];

  const int  tid  = threadIdx.x;
  const long base = (long)blockIdx.x * NPB;

  // ---- Phase 1: per-node neighbor select + 1/d^2 scale (once per node)
  if (tid < NPB) {
    const float* row = feat + (base + tid) * NC;
    int i0 = (int)row[F];
    int i1 = (int)row[F + 1];
    int sel = (i1 != 0) ? i1 : i0;
    float alive = (i1 != 0 || i0 != 0) ? 1.f : 0.f;
    const float* nrow = feat + (long)sel * NC;
    float dx = row[0] - nrow[0];
    float dy = row[1] - nrow[1];
    float dz = row[2] - nrow[2];
    float d2 = dx * dx + dy * dy + dz * dz;
    s_sel[tid]   = sel;
    s_alive[tid] = alive;
    s_cs[tid]    = alive * ((d2 > 0.f) ? (1.f / d2) : 10000.f);
  }
  __syncthreads();

  // ---- Phase 2: build 64x192 bf16 A-tile, 2 elems/thread/iter, coalesced.
  // Consecutive threads -> consecutive k within a node row (contiguous global).
  for (int e = tid; e < NPB * (KP / 2); e += THREADS) {
    int n  = e / (KP / 2);            // KP/2 = 96
    int kp = (e - n * (KP / 2)) * 2;  // even k
    const float* srow = feat + (base + n) * NC;
    int   sel   = s_sel[n];
    float cs    = s_cs[n];
    float alive = s_alive[n];
    const float* nrow = feat + (long)sel * NC;
    float v[2];
    #pragma unroll
    for (int j = 0; j < 2; ++j) {
      int k = kp + j;
      float x;
      if (k < F) {
        x = srow[k] * alive;
      } else if (k < 2 * F) {
        int kk = k - F;
        float nv = nrow[kk];
        float sv = (kk < 3) ? 0.f : srow[kk];
        x = (nv + sv) * cs;
      } else {
        x = 0.f;
      }
      v[j] = x;
    }
    uint pack = (uint)f2bf(v[0]) | ((uint)f2bf(v[1]) << 16);
    *(uint*)(&a_bf[n * LDK + kp]) = pack;
  }
  __syncthreads();

  // ---- Phase 3: MFMA. Wave w owns nodes base + w*16 .. +15.
  const int w    = tid >> 6;
  const int l    = tid & 63;
  const int lrow = l & 15;
  const int lk   = (l >> 4) << 3;
  const ushort* arow = a_bf + (w * 16 + lrow) * LDK;
  const bf16x8* wfv  = (const bf16x8*)wf;

  f32x4 acc[8];
  #pragma unroll
  for (int i = 0; i < 8; ++i) acc[i] = (f32x4)(0.f);

  #pragma unroll
  for (int ks = 0; ks < NKS; ++ks) {
    bf16x8 af = *(const bf16x8*)(arow + ks * 32 + lk);
    #pragma unroll
    for (int ct = 0; ct < 8; ++ct) {
      bf16x8 bfr = wfv[(ks * 8 + ct) * 64 + l];
      acc[ct] = __builtin_amdgcn_mfma_f32_16x16x32_bf16(af, bfr, acc[ct], 0, 0, 0);
    }
  }

  // C/D layout: col = lane&15, row = (lane>>4)*4 + reg  [learn_hip m89/m91]
  const long orow = base + w * 16 + ((l >> 4) << 2);
  const int  col  = l & 15;
  #pragma unroll
  for (int ct = 0; ct < 8; ++ct) {
    #pragma unroll
    for (int r = 0; r < 4; ++r) {
      out[(orow + r) * OC + ct * 16 + col] = acc[ct][r];
    }
  }
}

extern "C" void kernel_launch(void* const* d_in, const int* in_sizes, int n_in,
                              void* d_out, int out_size, void* d_ws, size_t ws_size,
                              hipStream_t stream) {
  const float* feat = (const float*)d_in[0];
  const float* w_s  = (const float*)d_in[1];
  const float* w_n  = (const float*)d_in[2];
  float* outp = (float*)d_out;
  ushort* wf = (ushort*)d_ws;  // 6*8*64*8 bf16 = 49152 bytes

  prep_w<<<dim3((NKS * 8 * 64 + 255) / 256), 256, 0, stream>>>(w_s, w_n, wf);
  rgc_fused<<<dim3(kNodes / NPB), THREADS, 0, stream>>>(feat, wf, outp);
}